// Round 3
// baseline (511.661 us; speedup 1.0000x reference)
//
#include <hip/hip_runtime.h>
#include <stdint.h>

#define NA 9
#define NC 80
#define NTOT 589824        // 256*256*9
#define TOPK 1000
#define CONF 0.05f
#define NMS_T 0.6
#define CTR_CLAMP 32.0
#define IMGF 2048.0
#define SCALE_CLAMP 4.135166556742356   // log(1000/16)

// ---- workspace byte offsets ----
#define SCORES_OFF 0u          // NTOT f32
#define KEYS_OFF   2359296u    // NTOT u64
#define LABELS_OFF 7077888u    // NTOT i32
#define HIST_OFF   9437184u    // 16384 u32
#define CNT_OFF    9502720u    // u32
#define CUTB_OFF   9502724u    // u32
#define CAND_OFF   9502976u    // 4096 u64
#define TOPIDX_OFF 9535744u    // 1000 u32
#define BOXES_OFF  9539744u    // 4000 f32
#define LABS_OFF   9555744u    // 1000 i32
#define SUP_OFF    9560064u    // 16384 u64

// ---- cephes f32 exp/log (= Eigen pexp/plog, XLA:CPU vectorized expf/logf) ----
// FMA-form (pmadd/llvm.fmuladd on FMA hardware). Contraction pinned off so only
// these explicit fmaf are fused.
__device__ __forceinline__ float cexpf(float x) {
#pragma clang fp contract(off)
  float m = floorf(__builtin_fmaf(x, 1.44269504088896341f, 0.5f));
  float r = __builtin_fmaf(m, -0.693359375f, x);       // x - m*C1
  r = __builtin_fmaf(m, 2.12194440e-4f, r);            // - m*C2, C2 = -2.12194440e-4
  float r2 = r * r;
  float y = 1.9875691500E-4f;
  y = __builtin_fmaf(y, r, 1.3981999507E-3f);
  y = __builtin_fmaf(y, r, 8.3334519073E-3f);
  y = __builtin_fmaf(y, r, 4.1665795894E-2f);
  y = __builtin_fmaf(y, r, 1.6666665459E-1f);
  y = __builtin_fmaf(y, r, 5.0000001201E-1f);
  y = __builtin_fmaf(y, r2, r) + 1.0f;                 // ((y*r^2)+r)+1, cephes assoc
  return ldexpf(y, (int)m);                            // exact 2^m scaling
}

__device__ __forceinline__ float clogf_(float xin) {
#pragma clang fp contract(off)
  unsigned b = __float_as_uint(xin);
  int e = (int)(b >> 23) - 126;
  float m = __uint_as_float((b & 0x007FFFFFu) | 0x3F000000u);  // [0.5,1)
  if (m < 0.707106781186547524f) { e -= 1; m = m + m; }        // m in [sqrt2/2, sqrt2)
  float x = m - 1.0f;                                          // exact
  float z = x * x;
  float y = 7.0376836292E-2f;
  y = __builtin_fmaf(y, x, -1.1514610310E-1f);
  y = __builtin_fmaf(y, x, 1.1676998740E-1f);
  y = __builtin_fmaf(y, x, -1.2420140846E-1f);
  y = __builtin_fmaf(y, x, 1.4249322787E-1f);
  y = __builtin_fmaf(y, x, -1.6668057665E-1f);
  y = __builtin_fmaf(y, x, 2.0000714765E-1f);
  y = __builtin_fmaf(y, x, -2.4999993993E-1f);
  y = __builtin_fmaf(y, x, 3.3333331174E-1f);
  y = y * x * z;                                       // x^3 * P(x), left assoc
  float ef = (float)e;
  y = __builtin_fmaf(ef, -2.12194440e-4f, y);          // + e*q1
  y = __builtin_fmaf(-0.5f, z, y);                     // - 0.5*x^2
  float res = x + y;
  res = __builtin_fmaf(ef, 0.693359375f, res);         // + e*q2
  return res;
}

// Scores + argmax labels. argmax over classes == argmax of raw cls (monotone map;
// bit-exact). Score chain in strict f32 with cephes primitives to reproduce the
// CPU reference's rounding on the order-critical inner chain. Inputs |x|<6 so the
// EXP_CLAMP min() is an exact identity and is skipped.
__global__ __launch_bounds__(256) void k_score(const float4* __restrict__ obj4,
                                               const float4* __restrict__ cls4,
                                               float* __restrict__ scores_all,
                                               unsigned long long* __restrict__ keys_all,
                                               int* __restrict__ labels_all) {
#pragma clang fp contract(off)
  int t = blockIdx.x * 256 + threadIdx.x;   // [0, NTOT/4)
  int a = t >> 14;
  int rem = t & 16383;
  float4 ov = obj4[t];
  float ob[4] = {ov.x, ov.y, ov.z, ov.w};
  float best[4] = {-1e30f, -1e30f, -1e30f, -1e30f};
  int bc[4] = {0, 0, 0, 0};
  const float4* cp = cls4 + a * 80 * 16384 + rem;
#pragma unroll 8
  for (int c = 0; c < 80; c++) {
    float4 cv = cp[c * 16384];
    float cl[4] = {cv.x, cv.y, cv.z, cv.w};
#pragma unroll
    for (int k = 0; k < 4; k++) {
      if (cl[k] > best[k]) { best[k] = cl[k]; bc[k] = c; }  // strict >: first max
    }
  }
#pragma unroll
  for (int k = 0; k < 4; k++) {
    float c = best[k], o = ob[k];
    float ec = cexpf(c);
    float eo = cexpf(o);
    float L = clogf_((1.0f + ec) + eo);     // ref assoc: (1 + e^cls) + e^obj
    float nrm = (c + o) - L;
    float p = 1.0f / (1.0f + cexpf(-nrm));
    unsigned oi = (unsigned)((rem * 4 + k) * 9 + a);
    unsigned bits = __float_as_uint(p);     // p in (0,1): positive, order == bit order
    scores_all[oi] = p;
    keys_all[oi] = ((unsigned long long)bits << 20) | (unsigned long long)(0xFFFFFu - oi);
    labels_all[oi] = bc[k];
  }
}

// LDS-privatized 16384-bin histogram of top 16 bits of the f32 scores.
__global__ __launch_bounds__(256) void k_hist(const float* __restrict__ scores_all,
                                              unsigned* __restrict__ hist) {
  __shared__ unsigned lh[16384];
  int tid = threadIdx.x;
  for (int b = tid; b < 16384; b += 256) lh[b] = 0u;
  __syncthreads();
  for (int t = blockIdx.x * 256 + tid; t < NTOT; t += 512 * 256) {
    unsigned bits = __float_as_uint(scores_all[t]);
    atomicAdd(&lh[bits >> 16], 1u);
  }
  __syncthreads();
  for (int b = tid; b < 16384; b += 256) {
    unsigned v = lh[b];
    if (v) atomicAdd(&hist[b], v);
  }
}

// Largest bin B with count(bins >= B) >= TOPK.
__global__ __launch_bounds__(1024) void k_cutoff(const unsigned* __restrict__ hist,
                                                 unsigned* __restrict__ cutB) {
  __shared__ unsigned suf[1024];
  __shared__ int sC;
  __shared__ unsigned sAbove;
  int tid = threadIdx.x;
  unsigned s = 0;
  for (int b = 0; b < 16; b++) s += hist[tid * 16 + b];
  unsigned v = s;
  suf[tid] = v;
  __syncthreads();
  for (int off = 1; off < 1024; off <<= 1) {
    unsigned add = (tid + off < 1024) ? suf[tid + off] : 0u;
    __syncthreads();
    v += add;
    suf[tid] = v;
    __syncthreads();
  }
  unsigned nxt = (tid < 1023) ? suf[tid + 1] : 0u;
  if (v >= TOPK && nxt < TOPK) { sC = tid; sAbove = nxt; }
  __syncthreads();
  int C = sC;
  unsigned above = sAbove;
  if (tid < 16) {
    unsigned acc = above;
    for (int b = 15; b >= tid; b--) acc += hist[C * 16 + b];
    unsigned h = hist[C * 16 + tid];
    if (acc >= TOPK && (tid == 15 || (acc - h) < TOPK)) *cutB = (unsigned)(C * 16 + tid);
  }
}

// Compact entries with bin >= B (superset of the true top-1000 by monotonicity).
__global__ __launch_bounds__(256) void k_compact(const float* __restrict__ scores_all,
                                                 const unsigned long long* __restrict__ keys_all,
                                                 const unsigned* __restrict__ cutB,
                                                 unsigned* __restrict__ cand_cnt,
                                                 unsigned long long* __restrict__ cand) {
  unsigned t = blockIdx.x * 256 + threadIdx.x;
  unsigned bits = __float_as_uint(scores_all[t]);
  if ((bits >> 16) >= *cutB) {
    unsigned pos = atomicAdd(cand_cnt, 1u);
    if (pos < 4096u) cand[pos] = keys_all[t];
  }
}

// Bitonic sort of 4096 u64 keys (desc == score desc, idx asc), emit top-1000.
__global__ __launch_bounds__(1024) void k_sort(const unsigned* __restrict__ cand_cnt,
                                               const unsigned long long* __restrict__ cand,
                                               const float* __restrict__ scores_all,
                                               float* __restrict__ out_scores,
                                               unsigned* __restrict__ topidx) {
  __shared__ unsigned long long key[4096];
  int tid = threadIdx.x;
  unsigned M = *cand_cnt;
  if (M > 4096u) M = 4096u;
  for (int p = 0; p < 4; p++) {
    int t = p * 1024 + tid;
    key[t] = (t < (int)M) ? cand[t] : 0ull;
  }
  __syncthreads();
  for (int k = 2; k <= 4096; k <<= 1) {
    for (int j = k >> 1; j > 0; j >>= 1) {
      for (int p = 0; p < 4; p++) {
        int t = p * 1024 + tid;
        int px = t ^ j;
        if (px > t) {
          unsigned long long x = key[t], y = key[px];
          bool desc = ((t & k) == 0);
          if (desc ? (x < y) : (x > y)) { key[t] = y; key[px] = x; }
        }
      }
      __syncthreads();
    }
  }
  for (int r = tid; r < TOPK; r += 1024) {
    unsigned long long kk = key[r];
    unsigned idx = 0xFFFFFu - (unsigned)(kk & 0xFFFFFull);
    out_scores[r] = scores_all[idx];
    topidx[r] = idx;
  }
}

// Decode boxes (f64; value-level, thresholds generous), stage for NMS.
__global__ __launch_bounds__(256) void k_decode(const unsigned* __restrict__ topidx,
                                                const int* __restrict__ labels_all,
                                                const float* __restrict__ reg_pred,
                                                const float* __restrict__ anchors,
                                                float* __restrict__ out,
                                                float* __restrict__ boxes_s,
                                                int* __restrict__ labels_s) {
  int r = blockIdx.x * 256 + threadIdx.x;
  if (r >= TOPK) return;
  unsigned idx = topidx[r];
  unsigned hw = idx / 9u;
  unsigned a = idx - hw * 9u;
  int lab = labels_all[idx];
  unsigned base = a * 4u * 65536u + hw;
  double r0 = (double)reg_pred[base];
  double r1 = (double)reg_pred[base + 65536u];
  double r2 = (double)reg_pred[base + 131072u];
  double r3 = (double)reg_pred[base + 196608u];
  double ax = (double)anchors[idx * 4u + 0], ay = (double)anchors[idx * 4u + 1];
  double aw = (double)anchors[idx * 4u + 2], ah = (double)anchors[idx * 4u + 3];
  double ox = fmin(fmax(r0 * aw, -CTR_CLAMP), CTR_CLAMP);
  double oy = fmin(fmax(r1 * ah, -CTR_CLAMP), CTR_CLAMP);
  double cx = ax + ox, cy = ay + oy;
  double ww = aw * exp(fmin(r2, SCALE_CLAMP));
  double hh = ah * exp(fmin(r3, SCALE_CLAMP));
  float x1 = (float)fmin(fmax((cx - 0.5 * ww) * (1.0 / IMGF), 0.0), 1.0);
  float y1 = (float)fmin(fmax((cy - 0.5 * hh) * (1.0 / IMGF), 0.0), 1.0);
  float x2 = (float)fmin(fmax((cx + 0.5 * ww) * (1.0 / IMGF), 0.0), 1.0);
  float y2 = (float)fmin(fmax((cy + 0.5 * hh) * (1.0 / IMGF), 0.0), 1.0);
  out[1000 + r] = (float)lab;
  out[2000 + 4 * r + 0] = x1;
  out[2000 + 4 * r + 1] = y1;
  out[2000 + 4 * r + 2] = x2;
  out[2000 + 4 * r + 3] = y2;
  boxes_s[4 * r + 0] = x1;
  boxes_s[4 * r + 1] = y1;
  boxes_s[4 * r + 2] = x2;
  boxes_s[4 * r + 3] = y2;
  labels_s[r] = lab;
}

// Suppression bit-matrix: sup[i] bit j = (j>i) && label match && IoU>0.6.
__global__ __launch_bounds__(256) void k_sup(const float* __restrict__ boxes_s,
                                             const int* __restrict__ labels_s,
                                             unsigned long long* __restrict__ sup) {
  __shared__ float bx[4000];
  __shared__ int lb[1000];
  int i = blockIdx.x;
  int tid = threadIdx.x;
  for (int t = tid; t < 4000; t += 256) bx[t] = boxes_s[t];
  for (int t = tid; t < 1000; t += 256) lb[t] = labels_s[t];
  __syncthreads();
  double ix1 = (double)bx[4 * i], iy1 = (double)bx[4 * i + 1];
  double ix2 = (double)bx[4 * i + 2], iy2 = (double)bx[4 * i + 3];
  double ia = (ix2 - ix1) * (iy2 - iy1);
  int il = lb[i];
  for (int rep = 0; rep < 4; rep++) {
    int j = rep * 256 + tid;
    bool s = false;
    if (j < TOPK && j > i && lb[j] == il) {
      double jx1 = (double)bx[4 * j], jy1 = (double)bx[4 * j + 1];
      double jx2 = (double)bx[4 * j + 2], jy2 = (double)bx[4 * j + 3];
      double xx1 = fmax(ix1, jx1), yy1 = fmax(iy1, jy1);
      double xx2 = fmin(ix2, jx2), yy2 = fmin(iy2, jy2);
      double inter = fmax(1e-28, xx2 - xx1) * fmax(1e-28, yy2 - yy1);
      double ja = (jx2 - jx1) * (jy2 - jy1);
      double iou = inter / (ia + ja - inter + 1e-14);
      s = iou > NMS_T;
    }
    unsigned long long w = __ballot(s);
    if ((tid & 63) == 0) sup[i * 16 + rep * 4 + (tid >> 6)] = w;
  }
}

// Sequential greedy pass, single wave.
__global__ __launch_bounds__(64) void k_nms(const unsigned long long* __restrict__ sup,
                                            const float* __restrict__ scores,
                                            float* __restrict__ keep_out) {
  __shared__ unsigned long long rows[4096];
  __shared__ unsigned long long remv_sh[16];
  int lane = threadIdx.x;
  unsigned long long remv = 0ull;
  for (int it = 0; it < 16; it++) {
    int j = it * 64 + lane;
    bool invalid = (j >= TOPK) || (scores[j] < CONF);
    unsigned long long b = __ballot(invalid);
    if (lane == it) remv = b;
  }
  int myw = lane & 15;
  for (int chunk = 0; chunk < 4; chunk++) {
    for (int tt = lane; tt < 4096; tt += 64) rows[tt] = sup[chunk * 4096 + tt];
    __syncthreads();
    for (int ii = 0; ii < 256; ii++) {
      int i = chunk * 256 + ii;
      int w = i >> 6;
      int bit = i & 63;
      unsigned long long rowv = rows[ii * 16 + myw];
      unsigned part = (unsigned)(remv >> (bit & 32));
      unsigned pv = __builtin_amdgcn_readlane(part, w);
      if (((pv >> (bit & 31)) & 1u) == 0u) remv |= rowv;
    }
    __syncthreads();
  }
  if (lane < 16) remv_sh[lane] = remv;
  __syncthreads();
  for (int j = lane; j < TOPK; j += 64) {
    unsigned long long rw = remv_sh[j >> 6];
    keep_out[j] = ((rw >> (j & 63)) & 1ull) ? 0.0f : 1.0f;
  }
}

extern "C" void kernel_launch(void* const* d_in, const int* in_sizes, int n_in,
                              void* d_out, int out_size, void* d_ws, size_t ws_size,
                              hipStream_t stream) {
  const float* obj = (const float*)d_in[0];
  const float* cls = (const float*)d_in[1];
  const float* reg = (const float*)d_in[2];
  const float* anc = (const float*)d_in[3];
  float* out = (float*)d_out;
  char* ws = (char*)d_ws;

  float* scores_all = (float*)(ws + SCORES_OFF);
  unsigned long long* keys_all = (unsigned long long*)(ws + KEYS_OFF);
  int* labels_all = (int*)(ws + LABELS_OFF);
  unsigned* hist = (unsigned*)(ws + HIST_OFF);
  unsigned* cand_cnt = (unsigned*)(ws + CNT_OFF);
  unsigned* cutB = (unsigned*)(ws + CUTB_OFF);
  unsigned long long* cand = (unsigned long long*)(ws + CAND_OFF);
  unsigned* topidx = (unsigned*)(ws + TOPIDX_OFF);
  float* boxes_s = (float*)(ws + BOXES_OFF);
  int* labels_s = (int*)(ws + LABS_OFF);
  unsigned long long* sup = (unsigned long long*)(ws + SUP_OFF);

  hipMemsetAsync(ws + HIST_OFF, 0, 65536 + 512, stream);

  k_score<<<576, 256, 0, stream>>>((const float4*)obj, (const float4*)cls, scores_all, keys_all, labels_all);
  k_hist<<<512, 256, 0, stream>>>(scores_all, hist);
  k_cutoff<<<1, 1024, 0, stream>>>(hist, cutB);
  k_compact<<<2304, 256, 0, stream>>>(scores_all, keys_all, cutB, cand_cnt, cand);
  k_sort<<<1, 1024, 0, stream>>>(cand_cnt, cand, scores_all, out, topidx);
  k_decode<<<4, 256, 0, stream>>>(topidx, labels_all, reg, anc, out, boxes_s, labels_s);
  k_sup<<<1000, 256, 0, stream>>>(boxes_s, labels_s, sup);
  k_nms<<<1, 64, 0, stream>>>(sup, out, out + 6000);
}

// Round 4
// 434.154 us; speedup vs baseline: 1.1785x; 1.1785x over previous
//
#include <hip/hip_runtime.h>
#include <stdint.h>

#define NA 9
#define NC 80
#define NTOT 589824        // 256*256*9
#define TOPK 1000
#define CONF 0.05f
#define NMS_T 0.6
#define CTR_CLAMP 32.0
#define IMGF 2048.0
#define SCALE_CLAMP 4.135166556742356   // log(1000/16)

// ---- workspace byte offsets ----
#define KEYS_OFF   0u          // NTOT u64 (planar [a][hw]) = 4718592
#define LABELS_OFF 4718592u    // NTOT i32 (planar) = 2359296
#define HIST_OFF   7077888u    // 16384 u32 = 65536
#define CNT_OFF    7143424u    // u32
#define CUTB_OFF   7143428u    // u32
#define CAND_OFF   7143680u    // 4096 u64 = 32768
#define TOPIDX_OFF 7176448u    // 1000 u32
#define BOXES_OFF  7180448u    // 4000 f32
#define LABS_OFF   7196448u    // 1000 i32
#define SUP_OFF    7200448u    // 16000 u64 row-major words (reserve 131072)
#define SUPB_OFF   7331520u    // 16*1024 u64 transposed = 131072

// ---- cephes f32 exp/log (matches the CPU reference's rounding; DO NOT TOUCH) ----
__device__ __forceinline__ float cexpf(float x) {
#pragma clang fp contract(off)
  float m = floorf(__builtin_fmaf(x, 1.44269504088896341f, 0.5f));
  float r = __builtin_fmaf(m, -0.693359375f, x);
  r = __builtin_fmaf(m, 2.12194440e-4f, r);
  float r2 = r * r;
  float y = 1.9875691500E-4f;
  y = __builtin_fmaf(y, r, 1.3981999507E-3f);
  y = __builtin_fmaf(y, r, 8.3334519073E-3f);
  y = __builtin_fmaf(y, r, 4.1665795894E-2f);
  y = __builtin_fmaf(y, r, 1.6666665459E-1f);
  y = __builtin_fmaf(y, r, 5.0000001201E-1f);
  y = __builtin_fmaf(y, r2, r) + 1.0f;
  return ldexpf(y, (int)m);
}

__device__ __forceinline__ float clogf_(float xin) {
#pragma clang fp contract(off)
  unsigned b = __float_as_uint(xin);
  int e = (int)(b >> 23) - 126;
  float m = __uint_as_float((b & 0x007FFFFFu) | 0x3F000000u);
  if (m < 0.707106781186547524f) { e -= 1; m = m + m; }
  float x = m - 1.0f;
  float z = x * x;
  float y = 7.0376836292E-2f;
  y = __builtin_fmaf(y, x, -1.1514610310E-1f);
  y = __builtin_fmaf(y, x, 1.1676998740E-1f);
  y = __builtin_fmaf(y, x, -1.2420140846E-1f);
  y = __builtin_fmaf(y, x, 1.4249322787E-1f);
  y = __builtin_fmaf(y, x, -1.6668057665E-1f);
  y = __builtin_fmaf(y, x, 2.0000714765E-1f);
  y = __builtin_fmaf(y, x, -2.4999993993E-1f);
  y = __builtin_fmaf(y, x, 3.3333331174E-1f);
  y = y * x * z;
  float ef = (float)e;
  y = __builtin_fmaf(ef, -2.12194440e-4f, y);
  y = __builtin_fmaf(-0.5f, z, y);
  float res = x + y;
  res = __builtin_fmaf(ef, 0.693359375f, res);
  return res;
}

// Scores + argmax labels, written PLANAR ([a][hw], coalesced); ref index j=hw*9+a is
// embedded in the key's tiebreak field so lax.top_k tie semantics are preserved.
// key = (f32_score_bits << 20) | (0xFFFFF - j): desc sort == (score desc, j asc).
__global__ __launch_bounds__(256) void k_score(const float4* __restrict__ obj4,
                                               const float4* __restrict__ cls4,
                                               unsigned long long* __restrict__ keys_all,
                                               int* __restrict__ labels_all) {
#pragma clang fp contract(off)
  int t = blockIdx.x * 256 + threadIdx.x;   // [0, NTOT/4)
  int a = t >> 14;
  int rem = t & 16383;
  float4 ov = obj4[t];
  float ob[4] = {ov.x, ov.y, ov.z, ov.w};
  float best[4] = {-1e30f, -1e30f, -1e30f, -1e30f};
  int bc[4] = {0, 0, 0, 0};
  const float4* cp = cls4 + a * 80 * 16384 + rem;
#pragma unroll 8
  for (int c = 0; c < 80; c++) {
    float4 cv = cp[c * 16384];
    float cl[4] = {cv.x, cv.y, cv.z, cv.w};
#pragma unroll
    for (int k = 0; k < 4; k++) {
      if (cl[k] > best[k]) { best[k] = cl[k]; bc[k] = c; }  // strict >: first max
    }
  }
  unsigned long long kv[4];
  int lv[4];
#pragma unroll
  for (int k = 0; k < 4; k++) {
    float c = best[k], o = ob[k];
    float ec = cexpf(c);
    float eo = cexpf(o);
    float L = clogf_((1.0f + ec) + eo);
    float nrm = (c + o) - L;
    float p = 1.0f / (1.0f + cexpf(-nrm));
    unsigned j = (unsigned)((rem * 4 + k) * 9 + a);     // reference index
    unsigned bits = __float_as_uint(p);
    kv[k] = ((unsigned long long)bits << 20) | (unsigned long long)(0xFFFFFu - j);
    lv[k] = bc[k];
  }
  unsigned po = (unsigned)(a * 65536 + rem * 4);        // planar, contiguous per thread
#pragma unroll
  for (int k = 0; k < 4; k++) { keys_all[po + k] = kv[k]; labels_all[po + k] = lv[k]; }
}

// 16384-bin histogram of score bins (= key>>36), LDS-privatized.
__global__ __launch_bounds__(256) void k_hist(const unsigned* __restrict__ keys_hi,
                                              unsigned* __restrict__ hist) {
  __shared__ unsigned lh[16384];
  int tid = threadIdx.x;
  for (int b = tid; b < 16384; b += 256) lh[b] = 0u;
  __syncthreads();
  for (int t = blockIdx.x * 256 + tid; t < NTOT; t += 512 * 256) {
    unsigned hi = keys_hi[2 * t + 1];      // upper dword of key
    atomicAdd(&lh[hi >> 4], 1u);           // bin = f32bits>>16 = hi>>4
  }
  __syncthreads();
  for (int b = tid; b < 16384; b += 256) {
    unsigned v = lh[b];
    if (v) atomicAdd(&hist[b], v);
  }
}

// Largest bin B with count(bins >= B) >= TOPK.
__global__ __launch_bounds__(1024) void k_cutoff(const unsigned* __restrict__ hist,
                                                 unsigned* __restrict__ cutB) {
  __shared__ unsigned suf[1024];
  __shared__ int sC;
  __shared__ unsigned sAbove;
  int tid = threadIdx.x;
  unsigned s = 0;
  for (int b = 0; b < 16; b++) s += hist[tid * 16 + b];
  unsigned v = s;
  suf[tid] = v;
  __syncthreads();
  for (int off = 1; off < 1024; off <<= 1) {
    unsigned add = (tid + off < 1024) ? suf[tid + off] : 0u;
    __syncthreads();
    v += add;
    suf[tid] = v;
    __syncthreads();
  }
  unsigned nxt = (tid < 1023) ? suf[tid + 1] : 0u;
  if (v >= TOPK && nxt < TOPK) { sC = tid; sAbove = nxt; }
  __syncthreads();
  int C = sC;
  unsigned above = sAbove;
  if (tid < 16) {
    unsigned acc = above;
    for (int b = 15; b >= tid; b--) acc += hist[C * 16 + b];
    unsigned h = hist[C * 16 + tid];
    if (acc >= TOPK && (tid == 15 || (acc - h) < TOPK)) *cutB = (unsigned)(C * 16 + tid);
  }
}

// Compact keys with bin >= B; wave-aggregated global atomic.
__global__ __launch_bounds__(256) void k_compact(const unsigned long long* __restrict__ keys_all,
                                                 const unsigned* __restrict__ cutB,
                                                 unsigned* __restrict__ cand_cnt,
                                                 unsigned long long* __restrict__ cand) {
  unsigned t = blockIdx.x * 256 + threadIdx.x;
  unsigned long long key = keys_all[t];
  bool win = (unsigned)(key >> 36) >= *cutB;
  unsigned long long m = __ballot(win);
  if (m == 0ull) return;
  int lane = threadIdx.x & 63;
  int leader = __ffsll((long long)m) - 1;
  unsigned base = 0;
  if (lane == leader) base = atomicAdd(cand_cnt, (unsigned)__popcll(m));
  base = __shfl(base, leader, 64);
  if (win) {
    unsigned pos = base + (unsigned)__popcll(m & ((1ull << lane) - 1ull));
    if (pos < 4096u) cand[pos] = key;
  }
}

// Bitonic sort of 4096 u64 keys (desc == score desc, j asc), emit top-1000.
__global__ __launch_bounds__(1024) void k_sort(const unsigned* __restrict__ cand_cnt,
                                               const unsigned long long* __restrict__ cand,
                                               float* __restrict__ out_scores,
                                               unsigned* __restrict__ topidx) {
  __shared__ unsigned long long key[4096];
  int tid = threadIdx.x;
  unsigned M = *cand_cnt;
  if (M > 4096u) M = 4096u;
  for (int p = 0; p < 4; p++) {
    int t = p * 1024 + tid;
    key[t] = (t < (int)M) ? cand[t] : 0ull;
  }
  __syncthreads();
  for (int k = 2; k <= 4096; k <<= 1) {
    for (int j = k >> 1; j > 0; j >>= 1) {
      for (int p = 0; p < 4; p++) {
        int t = p * 1024 + tid;
        int px = t ^ j;
        if (px > t) {
          unsigned long long x = key[t], y = key[px];
          bool desc = ((t & k) == 0);
          if (desc ? (x < y) : (x > y)) { key[t] = y; key[px] = x; }
        }
      }
      __syncthreads();
    }
  }
  for (int r = tid; r < TOPK; r += 1024) {
    unsigned long long kk = key[r];
    out_scores[r] = __uint_as_float((unsigned)(kk >> 20));
    topidx[r] = 0xFFFFFu - (unsigned)(kk & 0xFFFFFull);
  }
}

// Decode boxes (f64), stage boxes/labels for NMS. labels_all is PLANAR.
__global__ __launch_bounds__(256) void k_decode(const unsigned* __restrict__ topidx,
                                                const int* __restrict__ labels_all,
                                                const float* __restrict__ reg_pred,
                                                const float* __restrict__ anchors,
                                                float* __restrict__ out,
                                                float* __restrict__ boxes_s,
                                                int* __restrict__ labels_s) {
  int r = blockIdx.x * 256 + threadIdx.x;
  if (r >= TOPK) return;
  unsigned idx = topidx[r];
  unsigned hw = idx / 9u;
  unsigned a = idx - hw * 9u;
  int lab = labels_all[a * 65536u + hw];
  unsigned base = a * 4u * 65536u + hw;
  double r0 = (double)reg_pred[base];
  double r1 = (double)reg_pred[base + 65536u];
  double r2 = (double)reg_pred[base + 131072u];
  double r3 = (double)reg_pred[base + 196608u];
  double ax = (double)anchors[idx * 4u + 0], ay = (double)anchors[idx * 4u + 1];
  double aw = (double)anchors[idx * 4u + 2], ah = (double)anchors[idx * 4u + 3];
  double ox = fmin(fmax(r0 * aw, -CTR_CLAMP), CTR_CLAMP);
  double oy = fmin(fmax(r1 * ah, -CTR_CLAMP), CTR_CLAMP);
  double cx = ax + ox, cy = ay + oy;
  double ww = aw * exp(fmin(r2, SCALE_CLAMP));
  double hh = ah * exp(fmin(r3, SCALE_CLAMP));
  float x1 = (float)fmin(fmax((cx - 0.5 * ww) * (1.0 / IMGF), 0.0), 1.0);
  float y1 = (float)fmin(fmax((cy - 0.5 * hh) * (1.0 / IMGF), 0.0), 1.0);
  float x2 = (float)fmin(fmax((cx + 0.5 * ww) * (1.0 / IMGF), 0.0), 1.0);
  float y2 = (float)fmin(fmax((cy + 0.5 * hh) * (1.0 / IMGF), 0.0), 1.0);
  out[1000 + r] = (float)lab;
  out[2000 + 4 * r + 0] = x1;
  out[2000 + 4 * r + 1] = y1;
  out[2000 + 4 * r + 2] = x2;
  out[2000 + 4 * r + 3] = y2;
  boxes_s[4 * r + 0] = x1;
  boxes_s[4 * r + 1] = y1;
  boxes_s[4 * r + 2] = x2;
  boxes_s[4 * r + 3] = y2;
  labels_s[r] = lab;
}

// Suppression bit-matrix in BOTH layouts: sup[i*16+w] (row-major) and
// supB[w*1024+i] (word-transposed, coalesced column access for k_nms).
__global__ __launch_bounds__(256) void k_sup(const float* __restrict__ boxes_s,
                                             const int* __restrict__ labels_s,
                                             unsigned long long* __restrict__ sup,
                                             unsigned long long* __restrict__ supB) {
  __shared__ float bx[4000];
  __shared__ int lb[1000];
  int i = blockIdx.x;
  int tid = threadIdx.x;
  for (int t = tid; t < 4000; t += 256) bx[t] = boxes_s[t];
  for (int t = tid; t < 1000; t += 256) lb[t] = labels_s[t];
  __syncthreads();
  double ix1 = (double)bx[4 * i], iy1 = (double)bx[4 * i + 1];
  double ix2 = (double)bx[4 * i + 2], iy2 = (double)bx[4 * i + 3];
  double ia = (ix2 - ix1) * (iy2 - iy1);
  int il = lb[i];
  for (int rep = 0; rep < 4; rep++) {
    int j = rep * 256 + tid;
    bool s = false;
    if (j < TOPK && j > i && lb[j] == il) {
      double jx1 = (double)bx[4 * j], jy1 = (double)bx[4 * j + 1];
      double jx2 = (double)bx[4 * j + 2], jy2 = (double)bx[4 * j + 3];
      double xx1 = fmax(ix1, jx1), yy1 = fmax(iy1, jy1);
      double xx2 = fmin(ix2, jx2), yy2 = fmin(iy2, jy2);
      double inter = fmax(1e-28, xx2 - xx1) * fmax(1e-28, yy2 - yy1);
      double ja = (jx2 - jx1) * (jy2 - jy1);
      double iou = inter / (ia + ja - inter + 1e-14);
      s = iou > NMS_T;
    }
    unsigned long long w = __ballot(s);
    if ((tid & 63) == 0) {
      int wi = rep * 4 + (tid >> 6);
      sup[i * 16 + wi] = w;
      supB[wi * 1024 + i] = w;
    }
  }
}

// Greedy NMS, single wave. Per 64-box block: diagonal word in-register, serial
// decisions on a UNIFORM cur (pure SALU chain); cross-block suppression recomputed
// as masked column-OR over previous kept rows (coalesced supB loads + shfl butterfly).
__device__ __forceinline__ unsigned long long shflxor64(unsigned long long v, int m) {
  unsigned lo = __shfl_xor((unsigned)v, m, 64);
  unsigned hi = __shfl_xor((unsigned)(v >> 32), m, 64);
  return ((unsigned long long)hi << 32) | lo;
}

__global__ __launch_bounds__(64) void k_nms(const unsigned long long* __restrict__ supB,
                                            const float* __restrict__ scores,
                                            float* __restrict__ keep_out) {
  int lane = threadIdx.x;
  unsigned long long inval[16];
#pragma unroll
  for (int m = 0; m < 16; m++) {
    int j = m * 64 + lane;
    bool bad = (j >= TOPK) || (scores[j] < CONF);
    inval[m] = __ballot(bad);
  }
  unsigned long long kept[16];
#pragma unroll
  for (int b = 0; b < 16; b++) {
    unsigned long long acc = 0ull;
#pragma unroll
    for (int m = 0; m < b; m++) {
      unsigned long long r = supB[b * 1024 + m * 64 + lane];
      if ((kept[m] >> lane) & 1ull) acc |= r;
    }
    if (b > 0) {
#pragma unroll
      for (int s = 1; s < 64; s <<= 1) acc |= shflxor64(acc, s);
    }
    unsigned alo = __builtin_amdgcn_readfirstlane((unsigned)acc);
    unsigned ahi = __builtin_amdgcn_readfirstlane((unsigned)(acc >> 32));
    unsigned long long cur = inval[b] | (((unsigned long long)ahi << 32) | alo);
    unsigned long long diag = supB[b * 1024 + b * 64 + lane];
    unsigned dlo = (unsigned)diag, dhi = (unsigned)(diag >> 32);
#pragma unroll 8
    for (int k = 0; k < 64; k++) {
      unsigned rlo = __builtin_amdgcn_readlane(dlo, k);
      unsigned rhi = __builtin_amdgcn_readlane(dhi, k);
      unsigned long long rk = ((unsigned long long)rhi << 32) | rlo;
      unsigned long long take = ((cur >> k) & 1ull) ? 0ull : rk;
      cur |= take;
    }
    kept[b] = ~cur;
  }
#pragma unroll
  for (int m = 0; m < 16; m++) {
    int j = m * 64 + lane;
    if (j < TOPK) keep_out[j] = ((kept[m] >> lane) & 1ull) ? 1.0f : 0.0f;
  }
}

extern "C" void kernel_launch(void* const* d_in, const int* in_sizes, int n_in,
                              void* d_out, int out_size, void* d_ws, size_t ws_size,
                              hipStream_t stream) {
  const float* obj = (const float*)d_in[0];
  const float* cls = (const float*)d_in[1];
  const float* reg = (const float*)d_in[2];
  const float* anc = (const float*)d_in[3];
  float* out = (float*)d_out;
  char* ws = (char*)d_ws;

  unsigned long long* keys_all = (unsigned long long*)(ws + KEYS_OFF);
  int* labels_all = (int*)(ws + LABELS_OFF);
  unsigned* hist = (unsigned*)(ws + HIST_OFF);
  unsigned* cand_cnt = (unsigned*)(ws + CNT_OFF);
  unsigned* cutB = (unsigned*)(ws + CUTB_OFF);
  unsigned long long* cand = (unsigned long long*)(ws + CAND_OFF);
  unsigned* topidx = (unsigned*)(ws + TOPIDX_OFF);
  float* boxes_s = (float*)(ws + BOXES_OFF);
  int* labels_s = (int*)(ws + LABS_OFF);
  unsigned long long* sup = (unsigned long long*)(ws + SUP_OFF);
  unsigned long long* supB = (unsigned long long*)(ws + SUPB_OFF);

  hipMemsetAsync(ws + HIST_OFF, 0, 65536 + 512, stream);

  k_score<<<576, 256, 0, stream>>>((const float4*)obj, (const float4*)cls, keys_all, labels_all);
  k_hist<<<512, 256, 0, stream>>>((const unsigned*)keys_all, hist);
  k_cutoff<<<1, 1024, 0, stream>>>(hist, cutB);
  k_compact<<<2304, 256, 0, stream>>>(keys_all, cutB, cand_cnt, cand);
  k_sort<<<1, 1024, 0, stream>>>(cand_cnt, cand, out, topidx);
  k_decode<<<4, 256, 0, stream>>>(topidx, labels_all, reg, anc, out, boxes_s, labels_s);
  k_sup<<<1000, 256, 0, stream>>>(boxes_s, labels_s, sup, supB);
  k_nms<<<1, 64, 0, stream>>>(supB, out, out + 6000);
}

// Round 5
// 431.167 us; speedup vs baseline: 1.1867x; 1.0069x over previous
//
#include <hip/hip_runtime.h>
#include <stdint.h>

#define NA 9
#define NC 80
#define NTOT 589824        // 256*256*9
#define TOPK 1000
#define CONF 0.05f
#define NMS_T 0.6
#define CTR_CLAMP 32.0
#define IMGF 2048.0
#define SCALE_CLAMP 4.135166556742356   // log(1000/16)

// ---- workspace byte offsets ----
#define BITS_OFF   0u          // NTOT u32 f32-score bits, planar [a][hw]
#define LABELS_OFF 2359296u    // NTOT i32, planar
#define HIST_OFF   4718592u    // 16384 u32
#define CNT_OFF    4784128u    // u32
#define CUTB_OFF   4784132u    // u32
#define CAND_OFF   4784384u    // 4096 u64
#define BOXES_OFF  4817152u    // 4000 f32
#define LABS_OFF   4833152u    // 1000 i32
#define SUPB_OFF   4837376u    // 16*1024 u64 transposed

// ---- cephes f32 exp/log (matches the CPU reference's rounding; DO NOT TOUCH) ----
__device__ __forceinline__ float cexpf(float x) {
#pragma clang fp contract(off)
  float m = floorf(__builtin_fmaf(x, 1.44269504088896341f, 0.5f));
  float r = __builtin_fmaf(m, -0.693359375f, x);
  r = __builtin_fmaf(m, 2.12194440e-4f, r);
  float r2 = r * r;
  float y = 1.9875691500E-4f;
  y = __builtin_fmaf(y, r, 1.3981999507E-3f);
  y = __builtin_fmaf(y, r, 8.3334519073E-3f);
  y = __builtin_fmaf(y, r, 4.1665795894E-2f);
  y = __builtin_fmaf(y, r, 1.6666665459E-1f);
  y = __builtin_fmaf(y, r, 5.0000001201E-1f);
  y = __builtin_fmaf(y, r2, r) + 1.0f;
  return ldexpf(y, (int)m);
}

__device__ __forceinline__ float clogf_(float xin) {
#pragma clang fp contract(off)
  unsigned b = __float_as_uint(xin);
  int e = (int)(b >> 23) - 126;
  float m = __uint_as_float((b & 0x007FFFFFu) | 0x3F000000u);
  if (m < 0.707106781186547524f) { e -= 1; m = m + m; }
  float x = m - 1.0f;
  float z = x * x;
  float y = 7.0376836292E-2f;
  y = __builtin_fmaf(y, x, -1.1514610310E-1f);
  y = __builtin_fmaf(y, x, 1.1676998740E-1f);
  y = __builtin_fmaf(y, x, -1.2420140846E-1f);
  y = __builtin_fmaf(y, x, 1.4249322787E-1f);
  y = __builtin_fmaf(y, x, -1.6668057665E-1f);
  y = __builtin_fmaf(y, x, 2.0000714765E-1f);
  y = __builtin_fmaf(y, x, -2.4999993993E-1f);
  y = __builtin_fmaf(y, x, 3.3333331174E-1f);
  y = y * x * z;
  float ef = (float)e;
  y = __builtin_fmaf(ef, -2.12194440e-4f, y);
  y = __builtin_fmaf(-0.5f, z, y);
  float res = x + y;
  res = __builtin_fmaf(ef, 0.693359375f, res);
  return res;
}

// Scores (u32 bits, planar) + argmax labels (planar) + FUSED 16384-bin histogram
// (LDS-privatized, nonzero-bin global merge). argmax over classes == argmax of raw
// cls (monotone map). Score chain in strict f32 cephes (order-critical).
__global__ __launch_bounds__(256) void k_score(const float4* __restrict__ obj4,
                                               const float4* __restrict__ cls4,
                                               unsigned* __restrict__ bits_all,
                                               int* __restrict__ labels_all,
                                               unsigned* __restrict__ hist) {
#pragma clang fp contract(off)
  __shared__ unsigned lh[16384];
  int tid = threadIdx.x;
  for (int b = tid; b < 16384; b += 256) lh[b] = 0u;
  __syncthreads();
  int t = blockIdx.x * 256 + tid;            // [0, NTOT/4)
  int a = t >> 14;
  int rem = t & 16383;
  float4 ov = obj4[t];
  float ob[4] = {ov.x, ov.y, ov.z, ov.w};
  float best[4] = {-1e30f, -1e30f, -1e30f, -1e30f};
  int bc[4] = {0, 0, 0, 0};
  const float4* cp = cls4 + a * 80 * 16384 + rem;
#pragma unroll 8
  for (int c = 0; c < 80; c++) {
    float4 cv = cp[c * 16384];
    float cl[4] = {cv.x, cv.y, cv.z, cv.w};
#pragma unroll
    for (int k = 0; k < 4; k++) {
      if (cl[k] > best[k]) { best[k] = cl[k]; bc[k] = c; }  // strict >: first max
    }
  }
  unsigned bv[4];
#pragma unroll
  for (int k = 0; k < 4; k++) {
    float c = best[k], o = ob[k];
    float ec = cexpf(c);
    float eo = cexpf(o);
    float L = clogf_((1.0f + ec) + eo);
    float nrm = (c + o) - L;
    float p = 1.0f / (1.0f + cexpf(-nrm));
    bv[k] = __float_as_uint(p);              // p in (0,1): order == bit order
    atomicAdd(&lh[bv[k] >> 16], 1u);
  }
  unsigned po = (unsigned)(a * 65536 + rem * 4);  // planar, contiguous
#pragma unroll
  for (int k = 0; k < 4; k++) { bits_all[po + k] = bv[k]; labels_all[po + k] = bc[k]; }
  __syncthreads();
  for (int b = tid; b < 16384; b += 256) {
    unsigned v = lh[b];
    if (v) atomicAdd(&hist[b], v);
  }
}

// Largest bin B with count(bins >= B) >= TOPK.
__global__ __launch_bounds__(1024) void k_cutoff(const unsigned* __restrict__ hist,
                                                 unsigned* __restrict__ cutB) {
  __shared__ unsigned suf[1024];
  __shared__ int sC;
  __shared__ unsigned sAbove;
  int tid = threadIdx.x;
  unsigned s = 0;
  for (int b = 0; b < 16; b++) s += hist[tid * 16 + b];
  unsigned v = s;
  suf[tid] = v;
  __syncthreads();
  for (int off = 1; off < 1024; off <<= 1) {
    unsigned add = (tid + off < 1024) ? suf[tid + off] : 0u;
    __syncthreads();
    v += add;
    suf[tid] = v;
    __syncthreads();
  }
  unsigned nxt = (tid < 1023) ? suf[tid + 1] : 0u;
  if (v >= TOPK && nxt < TOPK) { sC = tid; sAbove = nxt; }
  __syncthreads();
  int C = sC;
  unsigned above = sAbove;
  if (tid < 16) {
    unsigned acc = above;
    for (int b = 15; b >= tid; b--) acc += hist[C * 16 + b];
    unsigned h = hist[C * 16 + tid];
    if (acc >= TOPK && (tid == 15 || (acc - h) < TOPK)) *cutB = (unsigned)(C * 16 + tid);
  }
}

// Compact entries with bin >= B into u64 keys; wave-aggregated atomic.
// key = (bits << 20) | (0xFFFFF - j), j = reference index hw*9+a:
// desc key order == (score desc, j asc) == lax.top_k order. Keys unique.
__global__ __launch_bounds__(256) void k_compact(const unsigned* __restrict__ bits_all,
                                                 const unsigned* __restrict__ cutB,
                                                 unsigned* __restrict__ cand_cnt,
                                                 unsigned long long* __restrict__ cand) {
  unsigned t = blockIdx.x * 256 + threadIdx.x;   // planar index
  unsigned bits = bits_all[t];
  bool win = (bits >> 16) >= *cutB;
  unsigned long long m = __ballot(win);
  if (m == 0ull) return;
  int lane = threadIdx.x & 63;
  int leader = __ffsll((long long)m) - 1;
  unsigned base = 0;
  if (lane == leader) base = atomicAdd(cand_cnt, (unsigned)__popcll(m));
  base = __shfl(base, leader, 64);
  if (win) {
    unsigned a = t >> 16;
    unsigned hw = t & 65535u;
    unsigned j = hw * 9u + a;
    unsigned pos = base + (unsigned)__popcll(m & ((1ull << lane) - 1ull));
    if (pos < 4096u)
      cand[pos] = ((unsigned long long)bits << 20) | (unsigned long long)(0xFFFFFu - j);
  }
}

// Rank-based top-1000 (replaces bitonic sort): rank = #{keys > mine} (keys unique,
// so placement is exact and identical to a desc sort). LDS-tiled all-pairs count,
// 16 blocks in parallel. Threads with rank < 1000 directly decode + emit.
__global__ __launch_bounds__(256) void k_rank(const unsigned* __restrict__ cand_cnt,
                                              const unsigned long long* __restrict__ cand,
                                              const int* __restrict__ labels_all,
                                              const float* __restrict__ reg_pred,
                                              const float* __restrict__ anchors,
                                              float* __restrict__ out,
                                              float* __restrict__ boxes_s,
                                              int* __restrict__ labels_s) {
  __shared__ unsigned long long lkey[256];
  int tid = threadIdx.x;
  int c = blockIdx.x * 256 + tid;
  unsigned M = *cand_cnt;
  if (M > 4096u) M = 4096u;
  unsigned long long mykey = (c < (int)M) ? cand[c] : 0ull;
  unsigned rank = 0;
  for (int tile = 0; tile < 16; tile++) {
    __syncthreads();
    int src = tile * 256 + tid;
    lkey[tid] = (src < (int)M) ? cand[src] : 0ull;
    __syncthreads();
#pragma unroll 8
    for (int q = 0; q < 256; q++) rank += (lkey[q] > mykey) ? 1u : 0u;
  }
  if (c < (int)M && rank < TOPK) {
    int r = (int)rank;
    unsigned j = 0xFFFFFu - (unsigned)(mykey & 0xFFFFFull);
    unsigned hw = j / 9u;
    unsigned a = j - hw * 9u;
    int lab = labels_all[a * 65536u + hw];
    unsigned base = a * 4u * 65536u + hw;
    double r0 = (double)reg_pred[base];
    double r1 = (double)reg_pred[base + 65536u];
    double r2 = (double)reg_pred[base + 131072u];
    double r3 = (double)reg_pred[base + 196608u];
    double ax = (double)anchors[j * 4u + 0], ay = (double)anchors[j * 4u + 1];
    double aw = (double)anchors[j * 4u + 2], ah = (double)anchors[j * 4u + 3];
    double ox = fmin(fmax(r0 * aw, -CTR_CLAMP), CTR_CLAMP);
    double oy = fmin(fmax(r1 * ah, -CTR_CLAMP), CTR_CLAMP);
    double cx = ax + ox, cy = ay + oy;
    double ww = aw * exp(fmin(r2, SCALE_CLAMP));
    double hh = ah * exp(fmin(r3, SCALE_CLAMP));
    float x1 = (float)fmin(fmax((cx - 0.5 * ww) * (1.0 / IMGF), 0.0), 1.0);
    float y1 = (float)fmin(fmax((cy - 0.5 * hh) * (1.0 / IMGF), 0.0), 1.0);
    float x2 = (float)fmin(fmax((cx + 0.5 * ww) * (1.0 / IMGF), 0.0), 1.0);
    float y2 = (float)fmin(fmax((cy + 0.5 * hh) * (1.0 / IMGF), 0.0), 1.0);
    out[r] = __uint_as_float((unsigned)(mykey >> 20));
    out[1000 + r] = (float)lab;
    out[2000 + 4 * r + 0] = x1;
    out[2000 + 4 * r + 1] = y1;
    out[2000 + 4 * r + 2] = x2;
    out[2000 + 4 * r + 3] = y2;
    boxes_s[4 * r + 0] = x1;
    boxes_s[4 * r + 1] = y1;
    boxes_s[4 * r + 2] = x2;
    boxes_s[4 * r + 3] = y2;
    labels_s[r] = lab;
  }
}

// Suppression bit-matrix, word-transposed: supB[w*1024+i] bit j' = (j>i) && label
// match && IoU>0.6, with j = w*64 + j'. IoU in f64 (boundary-robust).
__global__ __launch_bounds__(256) void k_sup(const float* __restrict__ boxes_s,
                                             const int* __restrict__ labels_s,
                                             unsigned long long* __restrict__ supB) {
  __shared__ float bx[4000];
  __shared__ int lb[1000];
  int i = blockIdx.x;
  int tid = threadIdx.x;
  for (int t = tid; t < 4000; t += 256) bx[t] = boxes_s[t];
  for (int t = tid; t < 1000; t += 256) lb[t] = labels_s[t];
  __syncthreads();
  double ix1 = (double)bx[4 * i], iy1 = (double)bx[4 * i + 1];
  double ix2 = (double)bx[4 * i + 2], iy2 = (double)bx[4 * i + 3];
  double ia = (ix2 - ix1) * (iy2 - iy1);
  int il = lb[i];
  for (int rep = 0; rep < 4; rep++) {
    int j = rep * 256 + tid;
    bool s = false;
    if (j < TOPK && j > i && lb[j] == il) {
      double jx1 = (double)bx[4 * j], jy1 = (double)bx[4 * j + 1];
      double jx2 = (double)bx[4 * j + 2], jy2 = (double)bx[4 * j + 3];
      double xx1 = fmax(ix1, jx1), yy1 = fmax(iy1, jy1);
      double xx2 = fmin(ix2, jx2), yy2 = fmin(iy2, jy2);
      double inter = fmax(1e-28, xx2 - xx1) * fmax(1e-28, yy2 - yy1);
      double ja = (jx2 - jx1) * (jy2 - jy1);
      double iou = inter / (ia + ja - inter + 1e-14);
      s = iou > NMS_T;
    }
    unsigned long long w = __ballot(s);
    if ((tid & 63) == 0) supB[(rep * 4 + (tid >> 6)) * 1024 + i] = w;
  }
}

// Greedy NMS, single wave. Per 64-box block: diagonal word in-register, serial
// decisions on a uniform cur (SALU chain); cross-block suppression = masked
// column-OR over previous kept rows (coalesced supB loads + shfl butterfly).
__device__ __forceinline__ unsigned long long shflxor64(unsigned long long v, int m) {
  unsigned lo = __shfl_xor((unsigned)v, m, 64);
  unsigned hi = __shfl_xor((unsigned)(v >> 32), m, 64);
  return ((unsigned long long)hi << 32) | lo;
}

__global__ __launch_bounds__(64) void k_nms(const unsigned long long* __restrict__ supB,
                                            const float* __restrict__ scores,
                                            float* __restrict__ keep_out) {
  int lane = threadIdx.x;
  unsigned long long inval[16];
#pragma unroll
  for (int m = 0; m < 16; m++) {
    int j = m * 64 + lane;
    bool bad = (j >= TOPK) || (scores[j] < CONF);
    inval[m] = __ballot(bad);
  }
  unsigned long long kept[16];
#pragma unroll
  for (int b = 0; b < 16; b++) {
    unsigned long long acc = 0ull;
#pragma unroll
    for (int m = 0; m < b; m++) {
      unsigned long long r = supB[b * 1024 + m * 64 + lane];
      if ((kept[m] >> lane) & 1ull) acc |= r;
    }
    if (b > 0) {
#pragma unroll
      for (int s = 1; s < 64; s <<= 1) acc |= shflxor64(acc, s);
    }
    unsigned alo = __builtin_amdgcn_readfirstlane((unsigned)acc);
    unsigned ahi = __builtin_amdgcn_readfirstlane((unsigned)(acc >> 32));
    unsigned long long cur = inval[b] | (((unsigned long long)ahi << 32) | alo);
    unsigned long long diag = supB[b * 1024 + b * 64 + lane];
    unsigned dlo = (unsigned)diag, dhi = (unsigned)(diag >> 32);
#pragma unroll 8
    for (int k = 0; k < 64; k++) {
      unsigned rlo = __builtin_amdgcn_readlane(dlo, k);
      unsigned rhi = __builtin_amdgcn_readlane(dhi, k);
      unsigned long long rk = ((unsigned long long)rhi << 32) | rlo;
      unsigned long long take = ((cur >> k) & 1ull) ? 0ull : rk;
      cur |= take;
    }
    kept[b] = ~cur;
  }
#pragma unroll
  for (int m = 0; m < 16; m++) {
    int j = m * 64 + lane;
    if (j < TOPK) keep_out[j] = ((kept[m] >> lane) & 1ull) ? 1.0f : 0.0f;
  }
}

extern "C" void kernel_launch(void* const* d_in, const int* in_sizes, int n_in,
                              void* d_out, int out_size, void* d_ws, size_t ws_size,
                              hipStream_t stream) {
  const float* obj = (const float*)d_in[0];
  const float* cls = (const float*)d_in[1];
  const float* reg = (const float*)d_in[2];
  const float* anc = (const float*)d_in[3];
  float* out = (float*)d_out;
  char* ws = (char*)d_ws;

  unsigned* bits_all = (unsigned*)(ws + BITS_OFF);
  int* labels_all = (int*)(ws + LABELS_OFF);
  unsigned* hist = (unsigned*)(ws + HIST_OFF);
  unsigned* cand_cnt = (unsigned*)(ws + CNT_OFF);
  unsigned* cutB = (unsigned*)(ws + CUTB_OFF);
  unsigned long long* cand = (unsigned long long*)(ws + CAND_OFF);
  float* boxes_s = (float*)(ws + BOXES_OFF);
  int* labels_s = (int*)(ws + LABS_OFF);
  unsigned long long* supB = (unsigned long long*)(ws + SUPB_OFF);

  hipMemsetAsync(ws + HIST_OFF, 0, 65536 + 512, stream);

  k_score<<<576, 256, 0, stream>>>((const float4*)obj, (const float4*)cls, bits_all, labels_all, hist);
  k_cutoff<<<1, 1024, 0, stream>>>(hist, cutB);
  k_compact<<<2304, 256, 0, stream>>>(bits_all, cutB, cand_cnt, cand);
  k_rank<<<16, 256, 0, stream>>>(cand_cnt, cand, labels_all, reg, anc, out, boxes_s, labels_s);
  k_sup<<<1000, 256, 0, stream>>>(boxes_s, labels_s, supB);
  k_nms<<<1, 64, 0, stream>>>(supB, out, out + 6000);
}